// Round 6
// baseline (566.427 us; speedup 1.0000x reference)
//
#include <hip/hip_runtime.h>
#include <cstdint>
#include <cstddef>

#define T_TOK 4096
#define DM 1024
#define HS 4096
#define NE 8
#define MAXROWS 10240  // 8192 pairs + 8*256 padding worst case
#define MAXTILES 40    // MAXROWS/256

typedef __attribute__((ext_vector_type(8))) short short8;
typedef __attribute__((ext_vector_type(4))) float floatx4;

__device__ __forceinline__ unsigned short f2bf(float f) {
  union { float f; unsigned u; } v; v.f = f;
  unsigned r = (v.u + 0x7fffu + ((v.u >> 16) & 1u)) >> 16;
  return (unsigned short)r;
}

__device__ __forceinline__ void gload_lds16(const void* g, void* l) {
  __builtin_amdgcn_global_load_lds((const __attribute__((address_space(1))) void*)g,
                                   (__attribute__((address_space(3))) void*)l, 16, 0, 0);
}

// s_barrier with compile-time memory fence only (no waitcnt drain)
#define BAR() asm volatile("s_barrier" ::: "memory")

// ---------------- small kernels ----------------

__global__ void k_cvt_init(const float* __restrict__ x, unsigned short* __restrict__ xb,
                           int* counts, int* cursor, unsigned* list) {
  int i = blockIdx.x * 256 + threadIdx.x;  // 4 elems per thread
  if (i < NE) { counts[i] = 0; cursor[i] = 0; }
  if (i < MAXROWS) list[i] = 0xFFFFFFFFu;
  float4 v = ((const float4*)x)[i];
  union { unsigned short us[4]; uint2 u2; } o;
  o.us[0] = f2bf(v.x); o.us[1] = f2bf(v.y); o.us[2] = f2bf(v.z); o.us[3] = f2bf(v.w);
  ((uint2*)xb)[i] = o.u2;
}

__global__ void k_route(const float* __restrict__ x, const float* __restrict__ rw,
                        const float* __restrict__ rb, const float* __restrict__ lw,
                        const float* __restrict__ lb, int* __restrict__ top_i,
                        float* __restrict__ top_p, int* __restrict__ counts) {
  int t = blockIdx.x * 4 + (threadIdx.x >> 6);
  int lane = threadIdx.x & 63;
  const float4* xt = (const float4*)(x + (size_t)t * DM);
  float4 xv[4];
#pragma unroll
  for (int j = 0; j < 4; j++) xv[j] = xt[lane * 4 + j];
  float dots[12];
#pragma unroll
  for (int r = 0; r < 12; r++) {
    const float4* wr = (const float4*)(r < 4 ? lw + r * DM : rw + (r - 4) * DM);
    float s = 0.f;
#pragma unroll
    for (int j = 0; j < 4; j++) {
      float4 w = wr[lane * 4 + j];
      s += xv[j].x * w.x + xv[j].y * w.y + xv[j].z * w.z + xv[j].w * w.w;
    }
#pragma unroll
    for (int o = 32; o > 0; o >>= 1) s += __shfl_xor(s, o, 64);
    dots[r] = s;
  }
  if (lane == 0) {
    float lp[4]; float m = -1e30f;
#pragma unroll
    for (int i = 0; i < 4; i++) { lp[i] = dots[i] + lb[i]; m = fmaxf(m, lp[i]); }
    float sum = 0.f;
#pragma unroll
    for (int i = 0; i < 4; i++) { lp[i] = expf(lp[i] - m); sum += lp[i]; }
#pragma unroll
    for (int i = 0; i < 4; i++) lp[i] /= sum;
    float ew[4];
    ew[0] = lp[0] + lp[1]; ew[1] = lp[1] + lp[2]; ew[2] = lp[2] + lp[3]; ew[3] = lp[3];
    float r8[8];
#pragma unroll
    for (int e = 0; e < 8; e++) r8[e] = dots[4 + e] + rb[e] + 0.1f * ew[e & 3];
    int e0 = 0;
#pragma unroll
    for (int e = 1; e < 8; e++) if (r8[e] > r8[e0]) e0 = e;
    int e1 = (e0 == 0) ? 1 : 0;
#pragma unroll
    for (int e = 0; e < 8; e++) if (e != e0 && r8[e] > r8[e1]) e1 = e;
    float tt = expf(r8[e1] - r8[e0]);
    float w0 = 1.f / (1.f + tt);
    float w1 = tt / (1.f + tt);
    top_i[t * 2] = e0; top_i[t * 2 + 1] = e1;
    top_p[t * 2] = w0; top_p[t * 2 + 1] = w1;
    atomicAdd(&counts[e0], 1); atomicAdd(&counts[e1], 1);
  }
}

__global__ void k_offsets(const int* counts, int* off) {
  if (threadIdx.x == 0) {
    int acc = 0;
    for (int e = 0; e < NE; e++) {
      off[e] = acc;
      int p = ((counts[e] + 255) >> 8) << 8;   // pad to 256 (tile M)
      acc += p;
    }
    off[NE] = acc;
  }
}

__global__ void k_scatter(const int* __restrict__ top_i, const int* __restrict__ off,
                          int* cursor, unsigned* __restrict__ list) {
  int t = blockIdx.x * 256 + threadIdx.x;
  if (t >= T_TOK) return;
#pragma unroll
  for (int k = 0; k < 2; k++) {
    int e = top_i[t * 2 + k];
    int pos = atomicAdd(&cursor[e], 1);
    list[off[e] + pos] = (unsigned)(t * 2 + k);
  }
}

// transpose+convert: src f32 [e][K][N] -> dst bf16 [e][N][K]
__global__ void k_transpose_bf16(const float* __restrict__ src, unsigned short* __restrict__ dst,
                                 int K, int N) {
  __shared__ float tile[64][65];
  const float* s = src + (size_t)blockIdx.z * K * N;
  unsigned short* d = dst + (size_t)blockIdx.z * K * N;
  int n0 = blockIdx.x * 64, k0 = blockIdx.y * 64;
  int tr = threadIdx.x >> 4;          // 0..15
  int tc = (threadIdx.x & 15) * 4;    // 0,4,...,60
#pragma unroll
  for (int j = 0; j < 4; j++) {
    int row = tr + j * 16;
    float4 v = *(const float4*)&s[(size_t)(k0 + row) * N + n0 + tc];
    tile[row][tc + 0] = v.x; tile[row][tc + 1] = v.y;
    tile[row][tc + 2] = v.z; tile[row][tc + 3] = v.w;
  }
  __syncthreads();
#pragma unroll
  for (int j = 0; j < 4; j++) {
    int n = tr + j * 16;
    union { unsigned short us[4]; uint2 u2; } o;
#pragma unroll
    for (int i = 0; i < 4; i++) o.us[i] = f2bf(tile[tc + i][n]);
    *(uint2*)&d[(size_t)(n0 + n) * K + k0 + tc] = o.u2;
  }
}

__global__ void k_init_out(const int* __restrict__ top_i, const float* __restrict__ top_p,
                           const float* __restrict__ b2, float* __restrict__ out) {
  int i = blockIdx.x * 256 + threadIdx.x;
  int t = i >> 10, d = i & 1023;
  int e0 = top_i[t * 2], e1 = top_i[t * 2 + 1];
  out[i] = top_p[t * 2] * b2[e0 * DM + d] + top_p[t * 2 + 1] * b2[e1 * DM + d];
}

// ---------------- grouped GEMM: 256x256, BK=64, counted-vmcnt 4-phase ----------------
// 8 waves (2M x 4N), per-wave 128x64, acc[8][4]. LDS 128KB (2 K-tile dbuf).
// Per K-tile, 4 quadrant phases (mh,nh); each phase: ds_read frags -> stage one
// half-tile (2 gload_lds) -> s_barrier -> 16 MFMA (setprio). ONE vmcnt(6) per
// K-tile (3 half-tiles stay in flight across barriers); vmcnt(0) only in tail.
// Stage placement honors WAR: A-halves of a buffer free after p3, B after p2.
//   p1: stage A1(t+1)->buf^1   p3: stage B0(t+2)->buf   p4: stage B1,A0(t+2)->buf
// MODE 0: h = gelu(xg @ w1t^T + b1)  (A gathered)            C bf16 -> Hout
// MODE 1: out += p * (h @ w2t^T)     (A linear, split-K)     atomicAdd f32
template <int MODE, int K, int N, int KT>
__global__ __launch_bounds__(512, 1) void k_gemm(
    const unsigned short* __restrict__ Abase,
    const unsigned short* __restrict__ Wt,   // [E][N][K] bf16
    const int* __restrict__ off, const unsigned* __restrict__ list,
    const float* __restrict__ bias, const float* __restrict__ top_p,
    unsigned short* __restrict__ Hout, float* __restrict__ out) {
  int gx = gridDim.x, gy = gridDim.y;
  int flat = (blockIdx.z * gy + blockIdx.y) * gx + blockIdx.x;
  int nwg = gx * gy * gridDim.z;
  int cpx = nwg >> 3;
  int swz = (flat & 7) * cpx + (flat >> 3);
  int bn = swz % gx; int rest = swz / gx;
  int bm = rest % gy; int z = rest / gy;
  int n0 = bn * 256, r0 = bm * 256;
  int kb = z * (KT * 64);
  int total = off[NE];
  if (r0 >= total) return;
  int e = 0;
  while (r0 >= off[e + 1]) ++e;

  __shared__ __align__(16) unsigned short lA[2][256 * 64];
  __shared__ __align__(16) unsigned short lB[2][256 * 64];
  __shared__ float sP[256];
  __shared__ int sTok[256];

  int tid = threadIdx.x;
  int w = tid >> 6, lane = tid & 63;
  int g8 = lane >> 3, c8 = lane & 7;     // staging: row-in-group, phys chunk
  int rowS = w * 8 + g8;                 // base row; load l adds l*64
  int koff = (c8 ^ g8) * 8;              // swizzled source k-elem offset (key=row&7)

  unsigned aOff[4], bOff[4];
#pragma unroll
  for (int l = 0; l < 4; l++) {
    int rowA = l * 64 + rowS;
    unsigned arow;
    if (MODE == 0) {
      unsigned pair = list[r0 + rowA];
      arow = (pair == 0xFFFFFFFFu) ? 0u : (pair >> 1);
    } else {
      arow = (unsigned)(r0 + rowA);
    }
    aOff[l] = arow * (unsigned)K + (unsigned)(kb + koff);
    bOff[l] = (unsigned)(e * N + n0 + rowA) * (unsigned)K + (unsigned)(kb + koff);
  }
  int ldsb = rowS * 64 + c8 * 8;         // ushort idx; load l adds l*4096

  if (MODE == 1 && tid < 256) {
    unsigned pair = list[r0 + tid];
    if (pair == 0xFFFFFFFFu) { sTok[tid] = -1; sP[tid] = 0.f; }
    else { sTok[tid] = (int)(pair >> 1); sP[tid] = top_p[pair]; }
  }

  // fragment geometry
  int wm = w >> 2, wn = w & 3;
  int lr = lane & 15, kq = lane >> 4;
  int rsel = lr & 7;

  floatx4 acc[8][4] = {};

  // half H of a tile = rows [H*128, H*128+128) -> loads l = 2H, 2H+1
#define STAGE_A_H(BUF, TT, H)                                                 \
  do {                                                                        \
    gload_lds16(Abase + aOff[2 * (H)] + (TT) * 64,                            \
                &lA[BUF][(2 * (H)) * 4096 + ldsb]);                           \
    gload_lds16(Abase + aOff[2 * (H) + 1] + (TT) * 64,                        \
                &lA[BUF][(2 * (H) + 1) * 4096 + ldsb]);                       \
  } while (0)
#define STAGE_B_H(BUF, TT, H)                                                 \
  do {                                                                        \
    gload_lds16(Wt + bOff[2 * (H)] + (TT) * 64,                               \
                &lB[BUF][(2 * (H)) * 4096 + ldsb]);                           \
    gload_lds16(Wt + bOff[2 * (H) + 1] + (TT) * 64,                           \
                &lB[BUF][(2 * (H) + 1) * 4096 + ldsb]);                       \
  } while (0)

  __syncthreads();  // full drain: metadata loads retired, sTok/sP published

  // prologue: tile0 fully (8 loads), tile1 B0,B1,A0 (6 loads)
  STAGE_A_H(0, 0, 0); STAGE_A_H(0, 0, 1);
  STAGE_B_H(0, 0, 0); STAGE_B_H(0, 0, 1);
  STAGE_B_H(1, 1, 0); STAGE_B_H(1, 1, 1);
  STAGE_A_H(1, 1, 0);
  asm volatile("s_waitcnt vmcnt(6)" ::: "memory");  // tile0 resident; 3 halves in flight
  BAR();

  int curb = 0;
  for (int t = 0; t < KT; ++t) {
    const short8* qA = (const short8*)lA[curb];
    const short8* qB = (const short8*)lB[curb];
    short8 a[4][2], b0[2][2], b1[2][2];
    // ---- p1: (mh0, nh0); stage A1(t+1) -> buf^1 ----
#pragma unroll
    for (int m = 0; m < 4; m++)
#pragma unroll
      for (int kk = 0; kk < 2; kk++)
        a[m][kk] = qA[(wm * 128 + m * 16 + lr) * 8 + ((kk * 4 + kq) ^ rsel)];
#pragma unroll
    for (int n = 0; n < 2; n++)
#pragma unroll
      for (int kk = 0; kk < 2; kk++)
        b0[n][kk] = qB[(wn * 64 + n * 16 + lr) * 8 + ((kk * 4 + kq) ^ rsel)];
    if (t + 1 < KT) STAGE_A_H(curb ^ 1, t + 1, 1);
    BAR();
    __builtin_amdgcn_s_setprio(1);
#pragma unroll
    for (int m = 0; m < 4; m++)
#pragma unroll
      for (int n = 0; n < 2; n++)
#pragma unroll
        for (int kk = 0; kk < 2; kk++)
          acc[m][n] = __builtin_amdgcn_mfma_f32_16x16x32_bf16(a[m][kk], b0[n][kk], acc[m][n], 0, 0, 0);
    __builtin_amdgcn_s_setprio(0);
    BAR();
    // ---- p2: (mh0, nh1) ----
#pragma unroll
    for (int n = 0; n < 2; n++)
#pragma unroll
      for (int kk = 0; kk < 2; kk++)
        b1[n][kk] = qB[(wn * 64 + 32 + n * 16 + lr) * 8 + ((kk * 4 + kq) ^ rsel)];
    BAR();
    __builtin_amdgcn_s_setprio(1);
#pragma unroll
    for (int m = 0; m < 4; m++)
#pragma unroll
      for (int n = 0; n < 2; n++)
#pragma unroll
        for (int kk = 0; kk < 2; kk++)
          acc[m][n + 2] = __builtin_amdgcn_mfma_f32_16x16x32_bf16(a[m][kk], b1[n][kk], acc[m][n + 2], 0, 0, 0);
    __builtin_amdgcn_s_setprio(0);
    BAR();
    // ---- p3: (mh1, nh0); stage B0(t+2) -> buf (B-halves free after p2) ----
#pragma unroll
    for (int m = 0; m < 4; m++)
#pragma unroll
      for (int kk = 0; kk < 2; kk++)
        a[m][kk] = qA[(wm * 128 + 64 + m * 16 + lr) * 8 + ((kk * 4 + kq) ^ rsel)];
    if (t + 2 < KT) STAGE_B_H(curb, t + 2, 0);
    BAR();
    __builtin_amdgcn_s_setprio(1);
#pragma unroll
    for (int m = 0; m < 4; m++)
#pragma unroll
      for (int n = 0; n < 2; n++)
#pragma unroll
        for (int kk = 0; kk < 2; kk++)
          acc[m + 4][n] = __builtin_amdgcn_mfma_f32_16x16x32_bf16(a[m][kk], b0[n][kk], acc[m + 4][n], 0, 0, 0);
    __builtin_amdgcn_s_setprio(0);
    BAR();
    // ---- p4: (mh1, nh1); stage B1,A0(t+2) -> buf (A free after p3) ----
    if (t + 2 < KT) {
      STAGE_B_H(curb, t + 2, 1);
      STAGE_A_H(curb, t + 2, 0);
      asm volatile("s_waitcnt vmcnt(6)" ::: "memory");  // tile t+1 resident
    } else {
      asm volatile("s_waitcnt vmcnt(0)" ::: "memory");  // tail drain
    }
    BAR();
    __builtin_amdgcn_s_setprio(1);
#pragma unroll
    for (int m = 0; m < 4; m++)
#pragma unroll
      for (int n = 0; n < 2; n++)
#pragma unroll
        for (int kk = 0; kk < 2; kk++)
          acc[m + 4][n + 2] = __builtin_amdgcn_mfma_f32_16x16x32_bf16(a[m][kk], b1[n][kk], acc[m + 4][n + 2], 0, 0, 0);
    __builtin_amdgcn_s_setprio(0);
    curb ^= 1;
  }
#undef STAGE_A_H
#undef STAGE_B_H

  // ---- epilogue ----
  if (MODE == 0) {
    float bcol[4];
#pragma unroll
    for (int n = 0; n < 4; n++) bcol[n] = bias[e * N + n0 + wn * 64 + n * 16 + lr];
#pragma unroll
    for (int m = 0; m < 8; m++)
#pragma unroll
      for (int n = 0; n < 4; n++)
#pragma unroll
        for (int g = 0; g < 4; g++) {
          int row = wm * 128 + m * 16 + kq * 4 + g;
          int col = wn * 64 + n * 16 + lr;
          float v = acc[m][n][g] + bcol[n];
          // tanh-GELU (max abs err ~3e-4 vs erf, inside bf16 margin)
          float u = v * (0.7978845608f + 0.0356774081f * v * v);
          float gl = v / (1.f + __expf(-2.f * u));
          Hout[(size_t)(r0 + row) * (size_t)N + n0 + col] = f2bf(gl);
        }
  } else {
#pragma unroll
    for (int m = 0; m < 8; m++)
#pragma unroll
      for (int g = 0; g < 4; g++) {
        int row = wm * 128 + m * 16 + kq * 4 + g;
        int tok = sTok[row];
        if (tok >= 0) {
          float p = sP[row];
#pragma unroll
          for (int n = 0; n < 4; n++) {
            int col = wn * 64 + n * 16 + lr;
            atomicAdd(&out[(size_t)tok * DM + n0 + col], p * acc[m][n][g]);
          }
        }
      }
  }
}

// ---------------- launch ----------------

extern "C" void kernel_launch(void* const* d_in, const int* in_sizes, int n_in,
                              void* d_out, int out_size, void* d_ws, size_t ws_size,
                              hipStream_t stream) {
  const float* x  = (const float*)d_in[0];
  const float* rw = (const float*)d_in[1];
  const float* rb = (const float*)d_in[2];
  const float* lw = (const float*)d_in[3];
  const float* lb = (const float*)d_in[4];
  const float* w1 = (const float*)d_in[5];
  const float* b1 = (const float*)d_in[6];
  const float* w2 = (const float*)d_in[7];
  const float* b2 = (const float*)d_in[8];
  float* out = (float*)d_out;
  char* ws = (char*)d_ws;

  int* counts = (int*)ws;
  int* cursor = (int*)(ws + 32);
  int* off    = (int*)(ws + 64);
  int* top_i  = (int*)(ws + 128);                       // 32 KB
  float* top_p = (float*)(ws + 128 + 32768);            // 32 KB
  unsigned* list = (unsigned*)(ws + 128 + 65536);       // 40 KB
  unsigned short* xb = (unsigned short*)(ws + 131072);                      // 8 MB
  unsigned short* wt = (unsigned short*)(ws + 131072 + 8388608);            // 64 MB (shared w1t/w2t)
  unsigned short* h  = (unsigned short*)(ws + 131072 + 8388608 + 67108864); // 80 MB

  k_cvt_init<<<dim3(T_TOK * DM / 4 / 256), dim3(256), 0, stream>>>(x, xb, counts, cursor, list);
  k_route<<<dim3(T_TOK / 4), dim3(256), 0, stream>>>(x, rw, rb, lw, lb, top_i, top_p, counts);
  k_offsets<<<dim3(1), dim3(64), 0, stream>>>(counts, off);
  k_scatter<<<dim3(T_TOK / 256), dim3(256), 0, stream>>>(top_i, off, cursor, list);
  k_transpose_bf16<<<dim3(HS / 64, DM / 64, NE), dim3(256), 0, stream>>>(w1, wt, DM, HS);
  k_init_out<<<dim3(T_TOK * DM / 256), dim3(256), 0, stream>>>(top_i, top_p, b2, out);
  k_gemm<0, DM, HS, DM / 64><<<dim3(HS / 256, MAXTILES, 1), dim3(512), 0, stream>>>(
      xb, wt, off, list, b1, top_p, h, nullptr);
  k_transpose_bf16<<<dim3(DM / 64, HS / 64, NE), dim3(256), 0, stream>>>(w2, wt, HS, DM);
  k_gemm<1, HS, DM, HS / 4 / 64><<<dim3(DM / 256, MAXTILES, 4), dim3(512), 0, stream>>>(
      h, wt, off, list, nullptr, top_p, nullptr, out);
}